// Round 11
// baseline (383.197 us; speedup 1.0000x reference)
//
#include <hip/hip_runtime.h>
#include <cfloat>

typedef unsigned short u16;
typedef unsigned int   u32;
typedef unsigned long long u64;
typedef __attribute__((ext_vector_type(8))) short short8;
typedef __attribute__((ext_vector_type(4))) float float4_;

#define NB   2
#define N1   4096
#define N2   32768
#define C1   128
#define C2   64
#define CIN  192      // C1 + C2
#define F1   128
#define F2   128
#define ROW0 131      // 3 + C1 (fp32)
#define ROW1 67       // 3 + C2 (fp32)
#define NQ   (NB * N2)   // 65536 total query points
#define EPSF 1e-07f
#define PADX 200      // LDS x-tile pitch (u16)
#define PADH 136      // LDS h-tile pitch (u16)

// ---- Morton sort geometry: 16^3 cells over [-4,4]^3 (clamped; boxes use real
// coords so outliers stay correct). 4096 cells/batch -> scan is tiny (R9 lesson:
// the 262144-cell scan was a hidden ~100s-of-us cost).
#define MG     16
#define NCELL  4096
#define MLO    (-4.0f)
#define MHINV  2.0f
#define NGROUP 64            // 4096 candidates / 64 per group
#define INFKEY 0x7F800000FFFFFFFFull

// round-to-nearest-even fp32 -> bf16 (finite data only)
__device__ __forceinline__ u16 f2bf(float f) {
  u32 x = __float_as_uint(f);
  return (u16)((x + 0x7fffu + ((x >> 16) & 1u)) >> 16);
}

struct KW { int i0, i1, i2; float w0, w1, w2; };   // 24 B

// u64 key = (d_bits<<32)|idx : one u64 compare == lexicographic (d, idx) ==
// lax.top_k's tie rule. Scan-order independent. (Validated R7/R8/R9.)
__device__ __forceinline__ void kins(u64 k, u64& k0, u64& k1, u64& k2) {
  bool lt0 = k < k0, lt1 = k < k1, lt2 = k < k2;
  k2 = lt1 ? k1 : (lt2 ? k : k2);
  k1 = lt0 ? k0 : (lt1 ? k : k1);
  k0 = lt0 ? k  : k0;
}

__device__ __forceinline__ int mcell(float x, float y, float z) {
  int cx = (int)((x - MLO) * MHINV); cx = cx < 0 ? 0 : (cx > MG-1 ? MG-1 : cx);
  int cy = (int)((y - MLO) * MHINV); cy = cy < 0 ? 0 : (cy > MG-1 ? MG-1 : cy);
  int cz = (int)((z - MLO) * MHINV); cz = cz < 0 ? 0 : (cz > MG-1 ? MG-1 : cz);
  // 4-bit Morton interleave -> spatially compact consecutive runs
  auto sp = [](int v) { return (v & 1) | ((v & 2) << 2) | ((v & 4) << 4) | ((v & 8) << 6); };
  return sp(cx) | (sp(cy) << 1) | (sp(cz) << 2);
}

// ---- repack weights + count candidates AND queries per Morton cell ------------
__global__ void repack_cnt(const float* __restrict__ W1, const float* __restrict__ W2,
                           u16* __restrict__ W1t, u16* __restrict__ W2t,
                           const float* __restrict__ in0, const float* __restrict__ in1,
                           int* __restrict__ ccnt, int* __restrict__ qcnt) {
  int i = blockIdx.x * 256 + threadIdx.x;
  if (i < F1 * CIN) { int n = i / CIN, k = i % CIN; W1t[i] = f2bf(W1[k * F1 + n]); }
  if (i < F2 * F1)  { int n = i / F1,  k = i % F1;  W2t[i] = f2bf(W2[k * F2 + n]); }
  if (i < NB * N1) {
    const float* r = in0 + (size_t)i * ROW0;
    int b = i >> 12;
    atomicAdd(&ccnt[b * NCELL + mcell(r[0], r[1], r[2])], 1);
  }
  if (i < NB * N2) {
    int b = i >> 15, n = i & (N2 - 1);
    const float* r = in1 + (size_t)(b * N2 + n) * ROW1;
    atomicAdd(&qcnt[b * NCELL + mcell(r[0], r[1], r[2])], 1);
  }
}

// ---- exclusive scan over 4096 cells (validated structure, right-sized now) ----
__global__ __launch_bounds__(1024) void mscan(int* __restrict__ ccnt,
                                              int* __restrict__ cstart,
                                              int* __restrict__ qcnt,
                                              int* __restrict__ qstart) {
  int b = blockIdx.x & 1, which = blockIdx.x >> 1, t = threadIdx.x;
  int* cnt = (which ? qcnt : ccnt) + b * NCELL;
  int* cs  = (which ? qstart : cstart) + b * (NCELL + 1);
  __shared__ int ps[1024];
  int base = t * 4;
  int sum = 0;
  for (int k = 0; k < 4; k++) sum += cnt[base + k];
  ps[t] = sum; __syncthreads();
  for (int off = 1; off < 1024; off <<= 1) {
    int v = (t >= off) ? ps[t - off] : 0; __syncthreads();
    ps[t] += v; __syncthreads();
  }
  int run = ps[t] - sum;
  for (int k = 0; k < 4; k++) {
    int s = cnt[base + k];
    cs[base + k] = run; cnt[base + k] = run;   // cursor := start
    run += s;
  }
  if (t == 1023) cs[NCELL] = run;
}

// ---- scatter candidates + queries into Morton order; xyz2 passthrough ---------
__global__ void scatter_all(const float* __restrict__ in0, const float* __restrict__ in1,
                            int* __restrict__ ccur, int* __restrict__ qcur,
                            float4* __restrict__ xyzs, float4* __restrict__ qxyz,
                            float* __restrict__ out) {
  int i = blockIdx.x * 256 + threadIdx.x;
  if (i < NB * N1) {
    const float* r = in0 + (size_t)i * ROW0;
    float x = r[0], y = r[1], z = r[2];
    int b = i >> 12, pi = i & (N1 - 1);
    int pos = atomicAdd(&ccur[b * NCELL + mcell(x, y, z)], 1);
    float4 v; v.x = x; v.y = y; v.z = z; v.w = __uint_as_float((u32)pi);
    xyzs[b * N1 + pos] = v;
  } else if (i < NB * N1 + NB * N2) {
    int j = i - NB * N1;
    int b = j >> 15, n = j & (N2 - 1);
    const float* r = in1 + (size_t)(b * N2 + n) * ROW1;
    float x = r[0], y = r[1], z = r[2];
    float* o = out + (size_t)NQ * F2 + (size_t)(b * N2 + n) * 3;  // passthrough
    o[0] = x; o[1] = y; o[2] = z;
    int pos = atomicAdd(&qcur[b * NCELL + mcell(x, y, z)], 1);
    float4 v; v.x = x; v.y = y; v.z = z; v.w = __uint_as_float((u32)n);
    qxyz[b * N2 + pos] = v;
  }
}

// ---- per-group bounding boxes: one wave per 64-candidate group ----------------
__global__ __launch_bounds__(256) void group_box(const float4* __restrict__ xyzs,
                                                 float4* __restrict__ gbox) {
  int wave = (blockIdx.x * 256 + threadIdx.x) >> 6;   // 0..127 (NB*NGROUP)
  int lane = threadIdx.x & 63;
  float4 p = xyzs[wave * 64 + lane];                  // b*N1 + g*64 + lane
  float lx = p.x, ly = p.y, lz = p.z, hx = p.x, hy = p.y, hz = p.z;
  for (int st = 32; st >= 1; st >>= 1) {
    lx = fminf(lx, __shfl_xor(lx, st)); hx = fmaxf(hx, __shfl_xor(hx, st));
    ly = fminf(ly, __shfl_xor(ly, st)); hy = fmaxf(hy, __shfl_xor(hy, st));
    lz = fminf(lz, __shfl_xor(lz, st)); hz = fmaxf(hz, __shfl_xor(hz, st));
  }
  if (lane == 0) {
    float4 lo; lo.x = lx; lo.y = ly; lo.z = lz; lo.w = 0.f;
    float4 hi; hi.x = hx; hi.y = hy; hi.z = hz; hi.w = 0.f;
    gbox[2 * wave] = lo; gbox[2 * wave + 1] = hi;
  }
}

// ---- kNN: 16 Morton-adjacent queries/wave x 4 sub-lanes; 64 dense groups ------
// Per group: per-lane box-distance test; skip iff NO lane needs it (ballot).
// Sound: d2s = quad-min of current partial d2 >= final merged d2, and
// m2 > d2s*1.0001 => every point's computed d > final d2 (margin covers the
// ~1e-7 rel fp error of m2 and d). Scanned groups: 16 candidates per sub-lane,
// exact RN distance sequence, lex-u64 insert (order-independent, validated).
__global__ __launch_bounds__(256) void knn_groups(
    const int* __restrict__ cstart, const float4* __restrict__ xyzs,
    const float4* __restrict__ gbox, const float4* __restrict__ qxyz,
    KW* __restrict__ kw) {
  int lane = threadIdx.x & 63;
  int wav = (blockIdx.x * 256 + threadIdx.x) >> 6;    // 0..4095
  int qL = lane >> 2, sub = lane & 3;
  int b = wav >> 11;                                  // 2048 waves per batch
  int wq = (wav & 2047) * 16;
  float4 qv = qxyz[b * N2 + wq + qL];
  float qx = qv.x, qy = qv.y, qz = qv.z;
  u32 n = __float_as_uint(qv.w);
  // home group: candidate sorted-position of the wave's first query's cell
  int h0 = cstart[b * (NCELL + 1) + mcell(qx, qy, qz)] >> 6;
  int h = __builtin_amdgcn_readfirstlane(h0);
  h = h > 63 ? 63 : h;
  const float4* xp = xyzs + b * N1;
  const float4* gb = gbox + b * (2 * NGROUP);
  u64 k0 = INFKEY, k1 = INFKEY, k2 = INFKEY;
  float d2s = FLT_MAX;
  for (int off = 0; off < 64; off++) {
    int soff = (off & 1) ? ((off + 1) >> 1) : -(off >> 1);   // 0,+1,-1,+2,-2,...
    int g = (h + soff) & 63;
    float4 lo = gb[2 * g], hi = gb[2 * g + 1];               // uniform -> s_load
    float ox = fmaxf(0.f, fmaxf(lo.x - qx, qx - hi.x));
    float oy = fmaxf(0.f, fmaxf(lo.y - qy, qy - hi.y));
    float oz = fmaxf(0.f, fmaxf(lo.z - qz, qz - hi.z));
    float m2 = ox * ox + oy * oy + oz * oz;
    bool need = !(m2 > d2s * 1.0001f);
    if (__ballot(need) == 0ull) continue;                    // wave-uniform skip
    int gbase = g * 64 + 16 * sub;
#pragma unroll 4
    for (int j = 0; j < 16; j++) {
      float4 pt = xp[gbase + j];            // 4 addrs/wave, L2-resident
      float dx = qx - pt.x, dy = qy - pt.y, dz = qz - pt.z;
      float d = __fadd_rn(__fadd_rn(__fmul_rn(dx, dx), __fmul_rn(dy, dy)),
                          __fmul_rn(dz, dz));               // exact ref order
      u64 k = ((u64)__float_as_uint(d) << 32) | (u32)__float_as_uint(pt.w);
      kins(k, k0, k1, k2);
    }
    float d2o = __uint_as_float((u32)(k2 >> 32));
    d2o = fminf(d2o, __shfl_xor(d2o, 1));
    d2o = fminf(d2o, __shfl_xor(d2o, 2));
    d2s = d2o;
  }
  // lex-merge the 4 sub-lanes (validated butterfly)
  for (int st = 1; st <= 2; st <<= 1) {
    u64 p0 = __shfl_xor(k0, st), p1 = __shfl_xor(k1, st), p2 = __shfl_xor(k2, st);
    kins(p0, k0, k1, k2); kins(p1, k0, k1, k2); kins(p2, k0, k1, k2);
  }
  if (sub == 0) {
    float d0 = __uint_as_float((u32)(k0 >> 32));
    float d1 = __uint_as_float((u32)(k1 >> 32));
    float d2 = __uint_as_float((u32)(k2 >> 32));
    float a0 = fmaxf(d0, EPSF), a1 = fmaxf(d1, EPSF), a2 = fmaxf(d2, EPSF);
    float w0 = 1.f / a0, w1 = 1.f / a1, w2 = 1.f / a2;
    float s = __fadd_rn(__fadd_rn(w0, w1), w2);
    KW o; o.i0 = (int)(u32)k0; o.i1 = (int)(u32)k1; o.i2 = (int)(u32)k2;
    o.w0 = w0 / s; o.w1 = w1 / s; o.w2 = w2 / s;
    kw[b * N2 + (int)n] = o;
  }
}

// ---- K3: interp + concat -> bf16 LDS -> MFMA MLP1 -> MFMA MLP2 -> fp32 out -----
// (reverted to the R6-measured-best version: serial kw loads, simple gather)
__global__ __launch_bounds__(256) void interp_mlp(
    const float* __restrict__ in0, const float* __restrict__ in1,
    const KW* __restrict__ kw,
    const u16* __restrict__ W1t, const float* __restrict__ b1,
    const u16* __restrict__ W2t, const float* __restrict__ b2,
    float* __restrict__ out) {
  __shared__ __align__(16) u16 xs[4][16][PADX];   // 25,600 B
  __shared__ __align__(16) u16 hs[4][16][PADH];   // 17,408 B
  int t = threadIdx.x;
  int wave = t >> 6, lane = t & 63;
  int l16 = lane & 15, quad = lane >> 4;
  int qbase = blockIdx.x * 64 + wave * 16;
  int b = qbase >> 15;                  // uniform per block

  for (int qi = 0; qi < 16; qi++) {
    int q = qbase + qi;
    KW k = kw[q];                       // wave-uniform load
    const float* base = in0 + (size_t)b * N1 * ROW0 + 3;
    const float* r0 = base + (size_t)k.i0 * ROW0;
    const float* r1 = base + (size_t)k.i1 * ROW0;
    const float* r2 = base + (size_t)k.i2 * ROW0;
    float lo = __fadd_rn(__fadd_rn(__fmul_rn(k.w0, r0[lane]),
                                   __fmul_rn(k.w1, r1[lane])),
                         __fmul_rn(k.w2, r2[lane]));
    float hi = __fadd_rn(__fadd_rn(__fmul_rn(k.w0, r0[64 + lane]),
                                   __fmul_rn(k.w1, r1[64 + lane])),
                         __fmul_rn(k.w2, r2[64 + lane]));
    xs[wave][qi][lane]      = f2bf(lo);
    xs[wave][qi][64 + lane] = f2bf(hi);
    int n2 = q & (N2 - 1);              // channels 128..191 = points2
    xs[wave][qi][C1 + lane] = f2bf(in1[(size_t)(b * N2 + n2) * ROW1 + 3 + lane]);
  }
  __syncthreads();

  float4_ acc[8];
#pragma unroll
  for (int nt = 0; nt < 8; nt++) acc[nt] = (float4_)0.f;
#pragma unroll
  for (int k0 = 0; k0 < CIN; k0 += 32) {
    short8 af = *(const short8*)&xs[wave][l16][k0 + quad * 8];
#pragma unroll
    for (int nt = 0; nt < 8; nt++) {
      short8 bf = *(const short8*)(W1t + (size_t)(nt * 16 + l16) * CIN + k0 + quad * 8);
      acc[nt] = __builtin_amdgcn_mfma_f32_16x16x32_bf16(af, bf, acc[nt], 0, 0, 0);
    }
  }
#pragma unroll
  for (int nt = 0; nt < 8; nt++) {
    float bv = b1[nt * 16 + l16];
#pragma unroll
    for (int r = 0; r < 4; r++) {   // C/D: row=quad*4+r, col=nt*16+l16
      hs[wave][quad * 4 + r][nt * 16 + l16] = f2bf(fmaxf(acc[nt][r] + bv, 0.f));
    }
  }
  __syncthreads();

  float4_ a2[8];
#pragma unroll
  for (int nt = 0; nt < 8; nt++) a2[nt] = (float4_)0.f;
#pragma unroll
  for (int k0 = 0; k0 < F1; k0 += 32) {
    short8 af = *(const short8*)&hs[wave][l16][k0 + quad * 8];
#pragma unroll
    for (int nt = 0; nt < 8; nt++) {
      short8 bf = *(const short8*)(W2t + (size_t)(nt * 16 + l16) * F1 + k0 + quad * 8);
      a2[nt] = __builtin_amdgcn_mfma_f32_16x16x32_bf16(af, bf, a2[nt], 0, 0, 0);
    }
  }
#pragma unroll
  for (int nt = 0; nt < 8; nt++) {
    float bv = b2[nt * 16 + l16];
#pragma unroll
    for (int r = 0; r < 4; r++) {
      int row = qbase + quad * 4 + r;
      out[(size_t)row * F2 + nt * 16 + l16] = fmaxf(a2[nt][r] + bv, 0.f);
    }
  }
}

extern "C" void kernel_launch(void* const* d_in, const int* in_sizes, int n_in,
                              void* d_out, int out_size, void* d_ws, size_t ws_size,
                              hipStream_t stream) {
  const float *in0 = nullptr, *in1 = nullptr, *W1 = nullptr, *W2 = nullptr;
  const float *b1 = nullptr, *b2 = nullptr;
  for (int i = 0; i < n_in; i++) {
    const float* p = (const float*)d_in[i];
    switch (in_sizes[i]) {
      case 2 * N1 * ROW0: in0 = p; break;
      case 2 * N2 * ROW1: in1 = p; break;
      case CIN * F1:      W1  = p; break;
      case F1 * F2:       W2  = p; break;
      case F1:            (b1 ? b2 : b1) = p; break;
      default: break;
    }
  }
  if (!in0) in0 = (const float*)d_in[0];
  if (!in1) in1 = (const float*)d_in[1];
  if (!W1)  W1  = (const float*)d_in[2];
  if (!b1)  b1  = (const float*)d_in[3];
  if (!W2)  W2  = (const float*)d_in[4];
  if (!b2)  b2  = (const float*)d_in[5];

  float* out = (float*)d_out;   // fp32: x (65536*128) ++ xyz2 (65536*3)

  // ws layout (2.97 MB << proven 13.58 MB):
  //   W1t 49,152 | W2t 32,768 | kw 1,572,864 | ccnt 32,768 | qcnt 32,768
  //   | cstart 32,776 | qstart 32,776 (+pad) | xyzs 131,072 | qxyz 1,048,576
  //   | gbox 4,096
  char* ws = (char*)d_ws;
  u16*    W1t    = (u16*)(ws + 0);
  u16*    W2t    = (u16*)(ws + 49152);
  KW*     kw     = (KW*)(ws + 81920);
  int*    ccnt   = (int*)(ws + 1654784);
  int*    qcnt   = (int*)(ws + 1687552);
  int*    cstart = (int*)(ws + 1720320);
  int*    qstart = (int*)(ws + 1753096);
  float4* xyzs   = (float4*)(ws + 1785888);
  float4* qxyz   = (float4*)(ws + 1916960);
  float4* gbox   = (float4*)(ws + 2965536);

  hipMemsetAsync(ccnt, 0, 65536, stream);   // ccnt + qcnt contiguous
  repack_cnt<<<dim3(256), dim3(256), 0, stream>>>(W1, W2, W1t, W2t, in0, in1, ccnt, qcnt);
  mscan<<<dim3(4), dim3(1024), 0, stream>>>(ccnt, cstart, qcnt, qstart);
  scatter_all<<<dim3(288), dim3(256), 0, stream>>>(in0, in1, ccnt, qcnt, xyzs, qxyz, out);
  group_box<<<dim3(32), dim3(256), 0, stream>>>(xyzs, gbox);
  knn_groups<<<dim3(1024), dim3(256), 0, stream>>>(cstart, xyzs, gbox, qxyz, kw);
  interp_mlp<<<dim3(NQ / 64), dim3(256), 0, stream>>>(in0, in1, kw, W1t, b1, W2t, b2, out);
}

// Round 12
// 241.693 us; speedup vs baseline: 1.5855x; 1.5855x over previous
//
#include <hip/hip_runtime.h>
#include <cfloat>

typedef unsigned short u16;
typedef unsigned int   u32;
typedef __attribute__((ext_vector_type(8))) short short8;
typedef __attribute__((ext_vector_type(4))) float float4_;

#define NB   2
#define N1   4096
#define N2   32768
#define C1   128
#define C2   64
#define CIN  192      // C1 + C2
#define F1   128
#define F2   128
#define ROW0 131      // 3 + C1 (fp32)
#define ROW1 67       // 3 + C2 (fp32)
#define NQ   (NB * N2)   // 65536 total query points
#define EPSF 1e-07f
#define KSPLIT 8
#define KCH  (N1 / KSPLIT)   // 512 candidates per tile
#define PADX 200      // LDS x/h-tile pitch (u16)

// round-to-nearest-even fp32 -> bf16 (finite data only)
__device__ __forceinline__ u16 f2bf(float f) {
  u32 x = __float_as_uint(f);
  return (u16)((x + 0x7fffu + ((x >> 16) & 1u)) >> 16);
}

// BRANCHLESS stable top-3 insert (merge path only). Strict <: earlier index wins.
__device__ __forceinline__ void ins3b(float d, int gi,
    float& d0, float& d1, float& d2, int& i0, int& i1, int& i2) {
  bool lt0 = d < d0, lt1 = d < d1, lt2 = d < d2;
  d2 = lt1 ? d1 : (lt2 ? d : d2);
  i2 = lt1 ? i1 : (lt2 ? gi : i2);
  d1 = lt0 ? d0 : (lt1 ? d : d1);
  i1 = lt0 ? i0 : (lt1 ? gi : i1);
  d0 = lt0 ? d : d0;
  i0 = lt0 ? gi : i0;
}

struct Part { float d0, d1, d2; int i0, i1, i2; };   // 24 B
struct KW   { int i0, i1, i2; float w0, w1, w2; };   // 24 B

// ---- repack: weights fp32 -> transposed bf16; candidate xyz -> packed float4 ---
__global__ void repack_w(const float* __restrict__ W1, const float* __restrict__ W2,
                         u16* __restrict__ W1t, u16* __restrict__ W2t,
                         const float* __restrict__ in0, float4* __restrict__ xyz1p) {
  int i = blockIdx.x * 256 + threadIdx.x;
  if (i < F1 * CIN) { int n = i / CIN, k = i % CIN; W1t[i] = f2bf(W1[k * F1 + n]); }
  if (i < F2 * F1)  { int n = i / F1,  k = i % F1;  W2t[i] = f2bf(W2[k * F2 + n]); }
  if (i < NB * N1)  {
    const float* r = in0 + (size_t)i * ROW0;
    xyz1p[i] = make_float4(r[0], r[1], r[2], 0.f);
  }
}

// ---- K1: kNN partial top-3, 512-candidate tile, exact 20-VALU inner loop -------
// (PROVEN: 124-127 us, issue-bound at the branchless-insert floor.)
// grid (NQ/256, KSPLIT) = 2048 blocks -> 8 blocks/CU, 32 waves/CU.
// Candidates from SGPRs (uniform s_load). Inner loop forced via inline asm:
// 8 dist (RN, exact ref order) + 3 v_cmp_nlt + 5 v_cndmask (all-VGPR + vcc;
// cndmask's vcc read occupies the constant bus -> gi must be VGPR) + min/med3
// value network + 1 v_mov. Also writes xyz2 passthrough from ct==0 blocks.
__global__ __launch_bounds__(256) void knn_part(const float4* __restrict__ xyz1p,
                                                const float* __restrict__ in1,
                                                Part* __restrict__ part,
                                                float* __restrict__ out) {
  int t = threadIdx.x;
  int bb = blockIdx.x >> 7;                   // batch: uniform, threadIdx-free
  int ct = blockIdx.y;
  int c0 = ct * KCH;
  const float4* __restrict__ src = xyz1p + (size_t)bb * N1 + c0;  // uniform base
  int q = blockIdx.x * 256 + t;
  int n = q & (N2 - 1);
  const float* qr = in1 + (size_t)(bb * N2 + n) * ROW1;
  float qx = qr[0], qy = qr[1], qz = qr[2];
  if (ct == 0) {                              // xyz2 passthrough
    float* o = out + (size_t)NQ * F2 + (size_t)q * 3;
    o[0] = qx; o[1] = qy; o[2] = qz;
  }
  float d0 = FLT_MAX, d1 = FLT_MAX, d2 = FLT_MAX;
  int   i0 = 0, i1 = 0, i2 = 0;
#pragma unroll 8
  for (int j = 0; j < KCH; j++) {
    float4 cc = src[j];                       // uniform -> s_load (SGPR broadcast)
    int gi = c0 + j;                          // scalar; "v" constraint -> v_mov
    float dx, dy, dz, vd; int tm;
    asm("v_subrev_f32 %[dx], %[cx], %[qx]\n\t"      // dx = qx - cx
        "v_subrev_f32 %[dy], %[cy], %[qy]\n\t"
        "v_subrev_f32 %[dz], %[cz], %[qz]\n\t"
        "v_mul_f32 %[dx], %[dx], %[dx]\n\t"
        "v_mul_f32 %[dy], %[dy], %[dy]\n\t"
        "v_mul_f32 %[dz], %[dz], %[dz]\n\t"
        "v_add_f32 %[dx], %[dx], %[dy]\n\t"         // (dx^2 + dy^2)
        "v_add_f32 %[vd], %[dx], %[dz]\n\t"         // + dz^2  (exact ref order)
        "v_cmp_nlt_f32 vcc, %[vd], %[d2]\n\t"       // vcc = !(d<d2)
        "v_cndmask_b32 %[tm], %[gi], %[i2], vcc\n\t"  // t2 = lt2 ? gi : i2
        "v_cmp_nlt_f32 vcc, %[vd], %[d1]\n\t"       // vcc = !(d<d1)
        "v_cndmask_b32 %[i2], %[i1], %[tm], vcc\n\t"  // i2 = lt1 ? i1 : t2
        "v_cndmask_b32 %[tm], %[gi], %[i1], vcc\n\t"  // t1 = lt1 ? gi : i1
        "v_cmp_nlt_f32 vcc, %[vd], %[d0]\n\t"       // vcc = !(d<d0)
        "v_cndmask_b32 %[i1], %[i0], %[tm], vcc\n\t"  // i1 = lt0 ? i0 : t1
        "v_cndmask_b32 %[i0], %[gi], %[i0], vcc\n\t"  // i0 = lt0 ? gi : i0
        "v_med3_f32 %[d2], %[vd], %[d1], %[d2]\n\t"   // nd2 (uses old d1,d2)
        "v_med3_f32 %[d1], %[d0], %[vd], %[d1]\n\t"   // nd1 (uses old d0,d1)
        "v_min_f32 %[d0], %[vd], %[d0]"               // nd0
        : [d0]"+v"(d0), [d1]"+v"(d1), [d2]"+v"(d2),
          [i0]"+v"(i0), [i1]"+v"(i1), [i2]"+v"(i2),
          [dx]"=&v"(dx), [dy]"=&v"(dy), [dz]"=&v"(dz),
          [vd]"=&v"(vd), [tm]"=&v"(tm)
        : [qx]"v"(qx), [qy]"v"(qy), [qz]"v"(qz),
          [cx]"s"(cc.x), [cy]"s"(cc.y), [cz]"s"(cc.z), [gi]"v"(gi)
        : "vcc");
  }
  Part p; p.d0 = d0; p.d1 = d1; p.d2 = d2; p.i0 = i0; p.i1 = i1; p.i2 = i2;
  part[((size_t)q << 3) + ct] = p;
}

// ---- K2 (FUSED): merge partials + interp + concat + MFMA MLP1/MLP2 -------------
// block = 256 = 4 waves; 64 queries/block; 1024 blocks.
// Fusion removes the knn_merge kernel (1 launch, ~10us class) and the 1.5MB kw
// global round-trip. Merge phase: threads 0..63 each merge their query's 8
// partials (192B contiguous/thread) into kwsh. One barrier (kwsh handoff).
// LDS: xs buffer REUSED as h-tile (both are strictly wave-private: wave w only
// touches xs[w]) -> 27KB total vs 43KB -> 4-5 blocks/CU instead of 3 for the
// latency-bound gather phase. No other barriers needed (all wave-private).
__global__ __launch_bounds__(256) void merge_interp(
    const float* __restrict__ in0, const float* __restrict__ in1,
    const Part* __restrict__ part,
    const u16* __restrict__ W1t, const float* __restrict__ b1,
    const u16* __restrict__ W2t, const float* __restrict__ b2,
    float* __restrict__ out) {
  __shared__ __align__(16) u16 xs[4][16][PADX];   // 25,600 B (xs, then h-tile)
  __shared__ KW kwsh[64];                         // 1,536 B
  int t = threadIdx.x;
  int wave = t >> 6, lane = t & 63;
  int l16 = lane & 15, quad = lane >> 4;
  int qbase = blockIdx.x * 64;
  int b = qbase >> 15;                  // uniform per block

  // ---- merge phase: threads 0..63, one query each (ascending tile order) ----
  if (t < 64) {
    int q = qbase + t;
    float d0 = FLT_MAX, d1 = FLT_MAX, d2 = FLT_MAX;
    int   i0 = 0, i1 = 0, i2 = 0;
#pragma unroll
    for (int ct = 0; ct < KSPLIT; ct++) {
      Part p = part[((size_t)q << 3) + ct];
      ins3b(p.d0, p.i0, d0, d1, d2, i0, i1, i2);
      ins3b(p.d1, p.i1, d0, d1, d2, i0, i1, i2);
      ins3b(p.d2, p.i2, d0, d1, d2, i0, i1, i2);
    }
    float a0 = fmaxf(d0, EPSF), a1 = fmaxf(d1, EPSF), a2 = fmaxf(d2, EPSF);
    float w0 = 1.f / a0, w1 = 1.f / a1, w2 = 1.f / a2;
    float s = __fadd_rn(__fadd_rn(w0, w1), w2);
    KW o; o.i0 = i0; o.i1 = i1; o.i2 = i2;
    o.w0 = w0 / s; o.w1 = w1 / s; o.w2 = w2 / s;
    kwsh[t] = o;
  }
  __syncthreads();                      // kwsh handoff (only barrier needed)

  // ---- gather + interp + concat into xs[wave] (16 x 192 bf16) ----
  int wq = wave * 16;
  const float* base   = in0 + (size_t)b * N1 * ROW0 + 3;
  for (int qi = 0; qi < 16; qi++) {
    KW k = kwsh[wq + qi];               // LDS broadcast
    const float* r0 = base + (size_t)k.i0 * ROW0;
    const float* r1 = base + (size_t)k.i1 * ROW0;
    const float* r2 = base + (size_t)k.i2 * ROW0;
    float lo = __fadd_rn(__fadd_rn(__fmul_rn(k.w0, r0[lane]),
                                   __fmul_rn(k.w1, r1[lane])),
                         __fmul_rn(k.w2, r2[lane]));
    float hi = __fadd_rn(__fadd_rn(__fmul_rn(k.w0, r0[64 + lane]),
                                   __fmul_rn(k.w1, r1[64 + lane])),
                         __fmul_rn(k.w2, r2[64 + lane]));
    xs[wave][qi][lane]      = f2bf(lo);
    xs[wave][qi][64 + lane] = f2bf(hi);
    int n2 = (qbase + wq + qi) & (N2 - 1);   // channels 128..191 = points2
    xs[wave][qi][C1 + lane] = f2bf(in1[(size_t)(b * N2 + n2) * ROW1 + 3 + lane]);
  }
  // no barrier: xs[wave] is wave-private from here on

  // GEMM1: h = relu(x @ W1 + b1); A from LDS, B from global (L1/L2-resident)
  float4_ acc[8];
#pragma unroll
  for (int nt = 0; nt < 8; nt++) acc[nt] = (float4_)0.f;
#pragma unroll
  for (int k0 = 0; k0 < CIN; k0 += 32) {
    short8 af = *(const short8*)&xs[wave][l16][k0 + quad * 8];
#pragma unroll
    for (int nt = 0; nt < 8; nt++) {
      short8 bf = *(const short8*)(W1t + (size_t)(nt * 16 + l16) * CIN + k0 + quad * 8);
      acc[nt] = __builtin_amdgcn_mfma_f32_16x16x32_bf16(af, bf, acc[nt], 0, 0, 0);
    }
  }
  // write h (bf16) back into the SAME xs[wave] tile (wave-private WAR; the
  // compiler orders ds_read/ds_write via lgkmcnt since aliasing is visible)
#pragma unroll
  for (int nt = 0; nt < 8; nt++) {
    float bv = b1[nt * 16 + l16];
#pragma unroll
    for (int r = 0; r < 4; r++) {   // C/D: row=quad*4+r, col=nt*16+l16
      xs[wave][quad * 4 + r][nt * 16 + l16] = f2bf(fmaxf(acc[nt][r] + bv, 0.f));
    }
  }

  // GEMM2: y = relu(h @ W2 + b2) -> fp32 global store
  float4_ a2[8];
#pragma unroll
  for (int nt = 0; nt < 8; nt++) a2[nt] = (float4_)0.f;
#pragma unroll
  for (int k0 = 0; k0 < F1; k0 += 32) {
    short8 af = *(const short8*)&xs[wave][l16][k0 + quad * 8];
#pragma unroll
    for (int nt = 0; nt < 8; nt++) {
      short8 bf = *(const short8*)(W2t + (size_t)(nt * 16 + l16) * F1 + k0 + quad * 8);
      a2[nt] = __builtin_amdgcn_mfma_f32_16x16x32_bf16(af, bf, a2[nt], 0, 0, 0);
    }
  }
#pragma unroll
  for (int nt = 0; nt < 8; nt++) {
    float bv = b2[nt * 16 + l16];
#pragma unroll
    for (int r = 0; r < 4; r++) {
      int row = qbase + wq + quad * 4 + r;
      out[(size_t)row * F2 + nt * 16 + l16] = fmaxf(a2[nt][r] + bv, 0.f);
    }
  }
}

extern "C" void kernel_launch(void* const* d_in, const int* in_sizes, int n_in,
                              void* d_out, int out_size, void* d_ws, size_t ws_size,
                              hipStream_t stream) {
  // input assignment by element count (ordering-invariant); positional fallback
  const float *in0 = nullptr, *in1 = nullptr, *W1 = nullptr, *W2 = nullptr;
  const float *b1 = nullptr, *b2 = nullptr;
  for (int i = 0; i < n_in; i++) {
    const float* p = (const float*)d_in[i];
    switch (in_sizes[i]) {
      case 2 * N1 * ROW0: in0 = p; break;
      case 2 * N2 * ROW1: in1 = p; break;
      case CIN * F1:      W1  = p; break;
      case F1 * F2:       W2  = p; break;
      case F1:            (b1 ? b2 : b1) = p; break;
      default: break;
    }
  }
  if (!in0) in0 = (const float*)d_in[0];
  if (!in1) in1 = (const float*)d_in[1];
  if (!W1)  W1  = (const float*)d_in[2];
  if (!b1)  b1  = (const float*)d_in[3];
  if (!W2)  W2  = (const float*)d_in[4];
  if (!b2)  b2  = (const float*)d_in[5];

  float* out = (float*)d_out;   // fp32: x (65536*128) ++ xyz2 (65536*3)

  // ws (13.58 MiB, proven): W1t 49,152 | W2t 32,768 | xyz1p 131,072 (in old kw
  // region) | part 12,582,912. kw buffer eliminated (merge fused into interp).
  char* ws = (char*)d_ws;
  u16*    W1t   = (u16*)(ws + 0);
  u16*    W2t   = (u16*)(ws + 49152);
  float4* xyz1p = (float4*)(ws + 81920);
  Part*   part  = (Part*)(ws + 1654784);

  repack_w<<<dim3(96), dim3(256), 0, stream>>>(W1, W2, W1t, W2t, in0, xyz1p);
  knn_part<<<dim3(NQ / 256, KSPLIT), dim3(256), 0, stream>>>(xyz1p, in1, part, out);
  merge_interp<<<dim3(NQ / 64), dim3(256), 0, stream>>>(in0, in1, part, W1t, b1, W2t, b2, out);
}

// Round 14
// 215.855 us; speedup vs baseline: 1.7753x; 1.1197x over previous
//
#include <hip/hip_runtime.h>
#include <cfloat>

typedef unsigned short u16;
typedef unsigned int   u32;
typedef __attribute__((ext_vector_type(8))) short short8;
typedef __attribute__((ext_vector_type(4))) float float4_;

#define NB   2
#define N1   4096
#define N2   32768
#define C1   128
#define C2   64
#define CIN  192      // C1 + C2
#define F1   128
#define F2   128
#define ROW0 131      // 3 + C1 (fp32)
#define ROW1 67       // 3 + C2 (fp32)
#define NQ   (NB * N2)   // 65536 total query points
#define EPSF 1e-07f
#define KSPLIT 4
#define KCH  (N1 / KSPLIT)   // 1024 candidates per tile
#define PADX 200      // LDS x/h-tile pitch (u16)

// round-to-nearest-even fp32 -> bf16 (finite data only)
__device__ __forceinline__ u16 f2bf(float f) {
  u32 x = __float_as_uint(f);
  return (u16)((x + 0x7fffu + ((x >> 16) & 1u)) >> 16);
}

// BRANCHLESS stable top-3 insert (merge path only). Strict <: earlier index wins.
__device__ __forceinline__ void ins3b(float d, int gi,
    float& d0, float& d1, float& d2, int& i0, int& i1, int& i2) {
  bool lt0 = d < d0, lt1 = d < d1, lt2 = d < d2;
  d2 = lt1 ? d1 : (lt2 ? d : d2);
  i2 = lt1 ? i1 : (lt2 ? gi : i2);
  d1 = lt0 ? d0 : (lt1 ? d : d1);
  i1 = lt0 ? i0 : (lt1 ? gi : i1);
  d0 = lt0 ? d : d0;
  i0 = lt0 ? gi : i0;
}

struct Part { float d0, d1, d2; int i0, i1, i2; };   // 24 B
struct KW   { int i0, i1, i2; float w0, w1, w2; };   // 24 B

// ---- repack: weights fp32 -> transposed bf16; candidate xyz -> packed float4 ---
__global__ void repack_w(const float* __restrict__ W1, const float* __restrict__ W2,
                         u16* __restrict__ W1t, u16* __restrict__ W2t,
                         const float* __restrict__ in0, float4* __restrict__ xyz1p) {
  int i = blockIdx.x * 256 + threadIdx.x;
  if (i < F1 * CIN) { int n = i / CIN, k = i % CIN; W1t[i] = f2bf(W1[k * F1 + n]); }
  if (i < F2 * F1)  { int n = i / F1,  k = i % F1;  W2t[i] = f2bf(W2[k * F2 + n]); }
  if (i < NB * N1)  {
    const float* r = in0 + (size_t)i * ROW0;
    xyz1p[i] = make_float4(r[0], r[1], r[2], 0.f);
  }
}

// ---- K1: kNN partial top-3 with wave-uniform insert early-out ------------------
// grid (NQ/256, KSPLIT=4) = 1024 blocks -> 4 blocks/CU, 16 waves/CU, 4 waves/SIMD
// (R2 proved this occupancy sustains ~83% VALU busy on the no-LDS s_load path).
// Early-out semantics HW-validated in R1: skip the insert iff NO lane has
// d < d2 (strict <). Per-lane no-op proof for d >= d2 >= d1 >= d0:
//   min(d,d0)=d0; med3(d0,d,d1)=d1; med3(d,d1,d2)=d2; lt0=lt1=lt2=false.
// cndmask rule used throughout: dst = vcc ? src1 : src0.
//   fast path: 8 dist + 1 cmp (+ s_cbranch)                 = 9 VALU slots
//   slow path: + 1 mov + 2 cmp + 5 cndmask + 2 med3 + 1 min = 20 slots
// Skip fraction at KCH=1024 ~ 50% -> avg ~14.5 slots vs proven 21 (R4: 125 us).
__global__ __launch_bounds__(256) void knn_part(const float4* __restrict__ xyz1p,
                                                const float* __restrict__ in1,
                                                Part* __restrict__ part,
                                                float* __restrict__ out) {
  int t = threadIdx.x;
  int bb = blockIdx.x >> 7;                   // batch: uniform, threadIdx-free
  int ct = blockIdx.y;
  int c0 = ct * KCH;
  const float4* __restrict__ src = xyz1p + (size_t)bb * N1 + c0;  // uniform base
  int q = blockIdx.x * 256 + t;
  int n = q & (N2 - 1);
  const float* qr = in1 + (size_t)(bb * N2 + n) * ROW1;
  float qx = qr[0], qy = qr[1], qz = qr[2];
  if (ct == 0) {                              // xyz2 passthrough
    float* o = out + (size_t)NQ * F2 + (size_t)q * 3;
    o[0] = qx; o[1] = qy; o[2] = qz;
  }
  float d0 = FLT_MAX, d1 = FLT_MAX, d2 = FLT_MAX;
  int   i0 = 0, i1 = 0, i2 = 0;
#pragma unroll 8
  for (int j = 0; j < KCH; j++) {
    float4 cc = src[j];                       // uniform -> s_load (SGPR broadcast)
    int gi = c0 + j;                          // SGPR; mov'd to VGPR on slow path
    float dx, dy, dz, vd; int tm, tg;
    asm("v_subrev_f32 %[dx], %[cx], %[qx]\n\t"      // dx = qx - cx
        "v_subrev_f32 %[dy], %[cy], %[qy]\n\t"
        "v_subrev_f32 %[dz], %[cz], %[qz]\n\t"
        "v_mul_f32 %[dx], %[dx], %[dx]\n\t"
        "v_mul_f32 %[dy], %[dy], %[dy]\n\t"
        "v_mul_f32 %[dz], %[dz], %[dz]\n\t"
        "v_add_f32 %[dx], %[dx], %[dy]\n\t"         // (dx^2 + dy^2)
        "v_add_f32 %[vd], %[dx], %[dz]\n\t"         // + dz^2  (exact ref order)
        "v_cmp_lt_f32 vcc, %[vd], %[d2]\n\t"        // vcc = lt2 (per lane)
        "s_cbranch_vccz Lskip%=\n\t"                // no lane inserts -> skip all
        "v_mov_b32 %[tg], %[gi]\n\t"                // gi -> VGPR (slow path only)
        "v_cndmask_b32 %[tm], %[i2], %[tg], vcc\n\t"  // t2 = lt2 ? gi : i2
        "v_cmp_lt_f32 vcc, %[vd], %[d1]\n\t"        // vcc = lt1
        "v_cndmask_b32 %[i2], %[tm], %[i1], vcc\n\t"  // i2 = lt1 ? i1 : t2
        "v_cndmask_b32 %[tm], %[i1], %[tg], vcc\n\t"  // t1 = lt1 ? gi : i1
        "v_cmp_lt_f32 vcc, %[vd], %[d0]\n\t"        // vcc = lt0
        "v_cndmask_b32 %[i1], %[tm], %[i0], vcc\n\t"  // i1 = lt0 ? i0 : t1
        "v_cndmask_b32 %[i0], %[i0], %[tg], vcc\n\t"  // i0 = lt0 ? gi : i0
        "v_med3_f32 %[d2], %[vd], %[d1], %[d2]\n\t"   // nd2 (old d1,d2)
        "v_med3_f32 %[d1], %[d0], %[vd], %[d1]\n\t"   // nd1 (old d0,d1)
        "v_min_f32 %[d0], %[vd], %[d0]\n\t"           // nd0
        "Lskip%=:"
        : [d0]"+v"(d0), [d1]"+v"(d1), [d2]"+v"(d2),
          [i0]"+v"(i0), [i1]"+v"(i1), [i2]"+v"(i2),
          [dx]"=&v"(dx), [dy]"=&v"(dy), [dz]"=&v"(dz),
          [vd]"=&v"(vd), [tm]"=&v"(tm), [tg]"=&v"(tg)
        : [qx]"v"(qx), [qy]"v"(qy), [qz]"v"(qz),
          [cx]"s"(cc.x), [cy]"s"(cc.y), [cz]"s"(cc.z), [gi]"s"(gi)
        : "vcc");
  }
  Part p; p.d0 = d0; p.d1 = d1; p.d2 = d2; p.i0 = i0; p.i1 = i1; p.i2 = i2;
  part[((size_t)q << 2) + ct] = p;
}

// ---- K2 (FUSED): merge partials + interp + concat + MFMA MLP1/MLP2 -------------
// (R12-proven structure; KSPLIT=4 merge)
__global__ __launch_bounds__(256) void merge_interp(
    const float* __restrict__ in0, const float* __restrict__ in1,
    const Part* __restrict__ part,
    const u16* __restrict__ W1t, const float* __restrict__ b1,
    const u16* __restrict__ W2t, const float* __restrict__ b2,
    float* __restrict__ out) {
  __shared__ __align__(16) u16 xs[4][16][PADX];   // 25,600 B (xs, then h-tile)
  __shared__ KW kwsh[64];                         // 1,536 B
  int t = threadIdx.x;
  int wave = t >> 6, lane = t & 63;
  int l16 = lane & 15, quad = lane >> 4;
  int qbase = blockIdx.x * 64;
  int b = qbase >> 15;                  // uniform per block

  if (t < 64) {
    int q = qbase + t;
    float d0 = FLT_MAX, d1 = FLT_MAX, d2 = FLT_MAX;
    int   i0 = 0, i1 = 0, i2 = 0;
#pragma unroll
    for (int ct = 0; ct < KSPLIT; ct++) {
      Part p = part[((size_t)q << 2) + ct];
      ins3b(p.d0, p.i0, d0, d1, d2, i0, i1, i2);
      ins3b(p.d1, p.i1, d0, d1, d2, i0, i1, i2);
      ins3b(p.d2, p.i2, d0, d1, d2, i0, i1, i2);
    }
    float a0 = fmaxf(d0, EPSF), a1 = fmaxf(d1, EPSF), a2 = fmaxf(d2, EPSF);
    float w0 = 1.f / a0, w1 = 1.f / a1, w2 = 1.f / a2;
    float s = __fadd_rn(__fadd_rn(w0, w1), w2);
    KW o; o.i0 = i0; o.i1 = i1; o.i2 = i2;
    o.w0 = w0 / s; o.w1 = w1 / s; o.w2 = w2 / s;
    kwsh[t] = o;
  }
  __syncthreads();                      // kwsh handoff (only barrier needed)

  int wq = wave * 16;
  const float* base = in0 + (size_t)b * N1 * ROW0 + 3;
  for (int qi = 0; qi < 16; qi++) {
    KW k = kwsh[wq + qi];               // LDS broadcast
    const float* r0 = base + (size_t)k.i0 * ROW0;
    const float* r1 = base + (size_t)k.i1 * ROW0;
    const float* r2 = base + (size_t)k.i2 * ROW0;
    float lo = __fadd_rn(__fadd_rn(__fmul_rn(k.w0, r0[lane]),
                                   __fmul_rn(k.w1, r1[lane])),
                         __fmul_rn(k.w2, r2[lane]));
    float hi = __fadd_rn(__fadd_rn(__fmul_rn(k.w0, r0[64 + lane]),
                                   __fmul_rn(k.w1, r1[64 + lane])),
                         __fmul_rn(k.w2, r2[64 + lane]));
    xs[wave][qi][lane]      = f2bf(lo);
    xs[wave][qi][64 + lane] = f2bf(hi);
    int n2 = (qbase + wq + qi) & (N2 - 1);
    xs[wave][qi][C1 + lane] = f2bf(in1[(size_t)(b * N2 + n2) * ROW1 + 3 + lane]);
  }

  float4_ acc[8];
#pragma unroll
  for (int nt = 0; nt < 8; nt++) acc[nt] = (float4_)0.f;
#pragma unroll
  for (int k0 = 0; k0 < CIN; k0 += 32) {
    short8 af = *(const short8*)&xs[wave][l16][k0 + quad * 8];
#pragma unroll
    for (int nt = 0; nt < 8; nt++) {
      short8 bf = *(const short8*)(W1t + (size_t)(nt * 16 + l16) * CIN + k0 + quad * 8);
      acc[nt] = __builtin_amdgcn_mfma_f32_16x16x32_bf16(af, bf, acc[nt], 0, 0, 0);
    }
  }
#pragma unroll
  for (int nt = 0; nt < 8; nt++) {
    float bv = b1[nt * 16 + l16];
#pragma unroll
    for (int r = 0; r < 4; r++) {   // C/D: row=quad*4+r, col=nt*16+l16
      xs[wave][quad * 4 + r][nt * 16 + l16] = f2bf(fmaxf(acc[nt][r] + bv, 0.f));
    }
  }

  float4_ a2[8];
#pragma unroll
  for (int nt = 0; nt < 8; nt++) a2[nt] = (float4_)0.f;
#pragma unroll
  for (int k0 = 0; k0 < F1; k0 += 32) {
    short8 af = *(const short8*)&xs[wave][l16][k0 + quad * 8];
#pragma unroll
    for (int nt = 0; nt < 8; nt++) {
      short8 bf = *(const short8*)(W2t + (size_t)(nt * 16 + l16) * F1 + k0 + quad * 8);
      a2[nt] = __builtin_amdgcn_mfma_f32_16x16x32_bf16(af, bf, a2[nt], 0, 0, 0);
    }
  }
#pragma unroll
  for (int nt = 0; nt < 8; nt++) {
    float bv = b2[nt * 16 + l16];
#pragma unroll
    for (int r = 0; r < 4; r++) {
      int row = qbase + wq + quad * 4 + r;
      out[(size_t)row * F2 + nt * 16 + l16] = fmaxf(a2[nt][r] + bv, 0.f);
    }
  }
}

extern "C" void kernel_launch(void* const* d_in, const int* in_sizes, int n_in,
                              void* d_out, int out_size, void* d_ws, size_t ws_size,
                              hipStream_t stream) {
  const float *in0 = nullptr, *in1 = nullptr, *W1 = nullptr, *W2 = nullptr;
  const float *b1 = nullptr, *b2 = nullptr;
  for (int i = 0; i < n_in; i++) {
    const float* p = (const float*)d_in[i];
    switch (in_sizes[i]) {
      case 2 * N1 * ROW0: in0 = p; break;
      case 2 * N2 * ROW1: in1 = p; break;
      case CIN * F1:      W1  = p; break;
      case F1 * F2:       W2  = p; break;
      case F1:            (b1 ? b2 : b1) = p; break;
      default: break;
    }
  }
  if (!in0) in0 = (const float*)d_in[0];
  if (!in1) in1 = (const float*)d_in[1];
  if (!W1)  W1  = (const float*)d_in[2];
  if (!b1)  b1  = (const float*)d_in[3];
  if (!W2)  W2  = (const float*)d_in[4];
  if (!b2)  b2  = (const float*)d_in[5];

  float* out = (float*)d_out;   // fp32: x (65536*128) ++ xyz2 (65536*3)

  // ws: W1t 49,152 | W2t 32,768 | xyz1p 131,072 | part 6,291,456 (KSPLIT=4)
  char* ws = (char*)d_ws;
  u16*    W1t   = (u16*)(ws + 0);
  u16*    W2t   = (u16*)(ws + 49152);
  float4* xyz1p = (float4*)(ws + 81920);
  Part*   part  = (Part*)(ws + 1654784);

  repack_w<<<dim3(96), dim3(256), 0, stream>>>(W1, W2, W1t, W2t, in0, xyz1p);
  knn_part<<<dim3(NQ / 256, KSPLIT), dim3(256), 0, stream>>>(xyz1p, in1, part, out);
  merge_interp<<<dim3(NQ / 64), dim3(256), 0, stream>>>(in0, in1, part, W1t, b1, W2t, b2, out);
}